// Round 2
// baseline (5744.120 us; speedup 1.0000x reference)
//
#include <hip/hip_runtime.h>
#include <hip/hip_fp16.h>

#define H 161
#define G4 644            // 4*H gates
#define BB 32             // batch
#define TT 1000           // time
#define M_TOT (BB*TT)     // 32000 rows
#define KPAD 192          // h vector padded to 192 halfs (4 quarters of 48)
#define KQ 24             // half2 pairs per quarter (48 halfs)

typedef _Float16 h2_t __attribute__((ext_vector_type(2)));

__device__ __forceinline__ h2_t bc_h2(unsigned int u) {
    return __builtin_bit_cast(h2_t, u);
}

__device__ __forceinline__ float dot2f(h2_t a, h2_t b, float c) {
#if __has_builtin(__builtin_amdgcn_fdot2)
    return __builtin_amdgcn_fdot2(a, b, c, false);
#else
    return c + (float)a[0] * (float)b[0] + (float)a[1] * (float)b[1];
#endif
}

__device__ __forceinline__ float sigm_f(float x) {
    return 1.0f / (1.0f + __expf(-x));
}
__device__ __forceinline__ float tanh_f(float x) {
    // 1 - 2/(e^{2x}+1); saturates correctly at +-inf without NaN
    return 1.0f - 2.0f / (__expf(2.0f * x) + 1.0f);
}

// In-quad sum: x += quad_perm shuffle of x. 0xB1 = [1,0,3,2] (xor 1),
// 0x4E = [2,3,0,1] (xor 2). VALU-pipe DPP, no LDS traffic. Quads are
// always fully active or fully inactive here, so DPP source lanes are safe.
template<int CTRL>
__device__ __forceinline__ float dpp_addf(float x) {
    int y = __builtin_amdgcn_update_dpp(0, __builtin_bit_cast(int, x), CTRL, 0xF, 0xF, true);
    return x + __builtin_bit_cast(float, y);
}
__device__ __forceinline__ float qsum(float x) {
    x = dpp_addf<0xB1>(x);
    x = dpp_addf<0x4E>(x);
    return x;
}

// Raw workgroup barrier that only drains LDS (lgkmcnt), NOT vmcnt:
// keeps hcat stores and pre prefetch loads in flight across the barrier.
__device__ __forceinline__ void bar_lds() {
    __builtin_amdgcn_sched_barrier(0);
    asm volatile("s_waitcnt lgkmcnt(0)" ::: "memory");
    __builtin_amdgcn_s_barrier();
    __builtin_amdgcn_sched_barrier(0);
}

// ---------------------------------------------------------------------------
// pre_gemm: pre[d][m][col*4+gate] = sum_k A[m][k]*wih_d[gate*H+col][k] + biases
// (gate-interleaved layout so lstm_scan's quad-per-column loads are coalesced)
// A: [M_TOT][H] fp32. Output half [2][M_TOT][G4].
// ---------------------------------------------------------------------------
__global__ __launch_bounds__(256) void pre_gemm(
    const float* __restrict__ A,
    const float* __restrict__ wf, const float* __restrict__ wb,
    const float* __restrict__ bif, const float* __restrict__ bhf,
    const float* __restrict__ bib, const float* __restrict__ bhb,
    __half* __restrict__ pre)
{
    const int BM = 64, BN = 64, BK = 16;
    int m0 = blockIdx.x * BM;
    int n0 = blockIdx.y * BN;           // n in [0, 1288) padded to 1344
    __shared__ float As[BK][BM + 1];
    __shared__ float Bs[BK][BN + 1];
    int tid = threadIdx.x;
    int tx = tid & 15, ty = tid >> 4;
    float acc[4][4] = {};

    for (int k0 = 0; k0 < H; k0 += BK) {
        #pragma unroll
        for (int l = 0; l < (BM * BK) / 256; ++l) {
            int e = tid + l * 256;
            int mm = e / BK, kk = e % BK;
            int k = k0 + kk;
            As[kk][mm] = (k < H) ? A[(size_t)(m0 + mm) * H + k] : 0.f;
        }
        #pragma unroll
        for (int l = 0; l < (BN * BK) / 256; ++l) {
            int e = tid + l * 256;
            int nn = e / BK, kk = e % BK;
            int n = n0 + nn, k = k0 + kk;
            float v = 0.f;
            if (k < H && n < 2 * G4)
                v = (n < G4) ? wf[(size_t)n * H + k] : wb[(size_t)(n - G4) * H + k];
            Bs[kk][nn] = v;
        }
        __syncthreads();
        #pragma unroll
        for (int kk = 0; kk < BK; ++kk) {
            float a4[4], b4[4];
            #pragma unroll
            for (int i = 0; i < 4; ++i) a4[i] = As[kk][ty + 16 * i];
            #pragma unroll
            for (int j = 0; j < 4; ++j) b4[j] = Bs[kk][tx + 16 * j];
            #pragma unroll
            for (int i = 0; i < 4; ++i)
                #pragma unroll
                for (int j = 0; j < 4; ++j) acc[i][j] += a4[i] * b4[j];
        }
        __syncthreads();
    }

    #pragma unroll
    for (int i = 0; i < 4; ++i) {
        int m = m0 + ty + 16 * i;
        #pragma unroll
        for (int j = 0; j < 4; ++j) {
            int n = n0 + tx + 16 * j;
            if (n < 2 * G4) {
                int d = (n >= G4) ? 1 : 0;
                int g = n - d * G4;
                int gate = g / H;
                int col = g - gate * H;
                float bias = d ? (bib[g] + bhb[g]) : (bif[g] + bhf[g]);
                pre[((size_t)d * M_TOT + m) * G4 + col * 4 + gate] =
                    __float2half(acc[i][j] + bias);
            }
        }
    }
}

// ---------------------------------------------------------------------------
// lstm_scan: one block per (batch, direction). 704 threads, quad layout:
// lanes (4q..4q+3) own column q. Lane s holds k-quarter s of all 4 gate
// weight rows (96 half2 VGPRs) and reads only quarter s of h from LDS
// (6 uint4 = 96 B/step, vs 336 B in the 1-gate-per-lane layout -> 3.5x
// less LDS return traffic, which was the measured bottleneck).
// Partial dots are all-reduced in-quad via DPP quad_perm butterfly; the
// c/h update is then done redundantly by all 4 lanes (no gate LDS
// round-trip) -> ONE barrier per step, h double-buffered in LDS.
// ---------------------------------------------------------------------------
__global__ __launch_bounds__(704, 1) void lstm_scan(
    const __half* __restrict__ pre,      // [2][M_TOT][G4], col*4+gate layout
    const float* __restrict__ whh_f,
    const float* __restrict__ whh_b,
    float* __restrict__ hcat)            // [M_TOT][2*H]
{
    const int b = blockIdx.x;            // 0..31
    const int d = blockIdx.y;            // 0,1
    const int tid = threadIdx.x;
    const float* whh = d ? whh_b : whh_f;

    __shared__ __align__(16) unsigned int h_sh[2][KPAD / 2];  // 2 x 192 halfs

    const bool active = tid < G4;
    const int q = tid >> 2;              // column 0..160
    const int s = tid & 3;               // k-quarter / seed-gate index

    // Weight quarters: w[g][i] = half2 of row (g*H + q), k = s*48 + 2i.
    h2_t w[4][KQ];
    if (active) {
        #pragma unroll
        for (int g = 0; g < 4; ++g) {
            const float* row = whh + (size_t)(g * H + q) * H;
            #pragma unroll
            for (int i = 0; i < KQ; ++i) {
                int k = s * 48 + 2 * i;
                float w0 = (k < H) ? row[k] : 0.f;
                float w1 = (k + 1 < H) ? row[k + 1] : 0.f;
                h2_t v; v[0] = (_Float16)w0; v[1] = (_Float16)w1;
                w[g][i] = v;
            }
        }
    }
    if (tid < KPAD / 2) { h_sh[0][tid] = 0u; h_sh[1][tid] = 0u; }

    float c = 0.f;
    const __half* pb = pre + ((size_t)d * M_TOT + (size_t)b * TT) * G4;
    const int tdir = d ? -1 : 1;
    const int t0 = d ? (TT - 1) : 0;

    // 2-deep pre prefetch. Unclamped t +- 1/2 offsets stay inside the
    // [2][M_TOT][G4] buffer for every (b,d) (checked for all corners).
    float pc = 0.f, p1 = 0.f;
    if (active) {
        pc = __half2float(pb[(long long)t0 * G4 + tid]);
        p1 = __half2float(pb[(long long)(t0 + tdir) * G4 + tid]);
    }
    __syncthreads();

    for (int ttt = 0; ttt < TT; ++ttt) {
        int t = d ? (TT - 1 - ttt) : ttt;
        float p2 = 0.f;
        if (active)
            p2 = __half2float(pb[(long long)(t + 2 * tdir) * G4 + tid]);

        if (active) {
            // Seed own gate's pre into its accumulator (static indexing).
            float a0 = (s == 0) ? pc : 0.f;
            float a1 = (s == 1) ? pc : 0.f;
            float a2 = (s == 2) ? pc : 0.f;
            float a3 = (s == 3) ? pc : 0.f;

            const uint4* h4 = (const uint4*)(h_sh[ttt & 1]);
            const int hb = s * (KQ / 4);        // 6 uint4 per quarter
            #pragma unroll
            for (int i = 0; i < KQ / 4; ++i) {
                uint4 hh = h4[hb + i];
                h2_t hx = bc_h2(hh.x), hy = bc_h2(hh.y);
                h2_t hz = bc_h2(hh.z), hw = bc_h2(hh.w);
                a0 = dot2f(w[0][4*i+0], hx, a0); a0 = dot2f(w[0][4*i+1], hy, a0);
                a0 = dot2f(w[0][4*i+2], hz, a0); a0 = dot2f(w[0][4*i+3], hw, a0);
                a1 = dot2f(w[1][4*i+0], hx, a1); a1 = dot2f(w[1][4*i+1], hy, a1);
                a1 = dot2f(w[1][4*i+2], hz, a1); a1 = dot2f(w[1][4*i+3], hw, a1);
                a2 = dot2f(w[2][4*i+0], hx, a2); a2 = dot2f(w[2][4*i+1], hy, a2);
                a2 = dot2f(w[2][4*i+2], hz, a2); a2 = dot2f(w[2][4*i+3], hw, a2);
                a3 = dot2f(w[3][4*i+0], hx, a3); a3 = dot2f(w[3][4*i+1], hy, a3);
                a3 = dot2f(w[3][4*i+2], hz, a3); a3 = dot2f(w[3][4*i+3], hw, a3);
            }
            // In-quad all-reduce: every lane gets all 4 full gate sums.
            a0 = qsum(a0); a1 = qsum(a1); a2 = qsum(a2); a3 = qsum(a3);

            float ig = sigm_f(a0);
            float fg = sigm_f(a1);
            float gg = tanh_f(a2);
            float og = sigm_f(a3);
            c = fg * c + ig * gg;                // all 4 lanes track identical c
            float h = og * tanh_f(c);
            if (s == 0) {
                hcat[((size_t)b * TT + t) * (2 * H) + (size_t)d * H + q] = h;
                ((__half*)h_sh[(ttt & 1) ^ 1])[q] = __float2half(h);
            }
        }
        bar_lds();
        pc = p1; p1 = p2;
    }
}

// ---------------------------------------------------------------------------
// lin_gemm: out[m][n] = relu?(sum_k hcat[m][k]*W[n][k] + bl[n]) + res[m][n]
// K = 2*H = 322, N = H = 161.
// ---------------------------------------------------------------------------
__global__ __launch_bounds__(256) void lin_gemm(
    const float* __restrict__ A,     // [M_TOT][2H]
    const float* __restrict__ W,     // [H][2H]
    const float* __restrict__ bl,    // [H]
    const float* __restrict__ res,   // [M_TOT][H]
    float* __restrict__ out,         // [M_TOT][H]
    int relu)
{
    const int BM = 64, BN = 64, BK = 16;
    const int K = 2 * H;
    int m0 = blockIdx.x * BM;
    int n0 = blockIdx.y * BN;        // up to 192 > 161, bounds-checked
    __shared__ float As[BK][BM + 1];
    __shared__ float Bs[BK][BN + 1];
    int tid = threadIdx.x;
    int tx = tid & 15, ty = tid >> 4;
    float acc[4][4] = {};

    for (int k0 = 0; k0 < K; k0 += BK) {
        #pragma unroll
        for (int l = 0; l < (BM * BK) / 256; ++l) {
            int e = tid + l * 256;
            int mm = e / BK, kk = e % BK;
            int k = k0 + kk;
            As[kk][mm] = (k < K) ? A[(size_t)(m0 + mm) * K + k] : 0.f;
        }
        #pragma unroll
        for (int l = 0; l < (BN * BK) / 256; ++l) {
            int e = tid + l * 256;
            int nn = e / BK, kk = e % BK;
            int n = n0 + nn, k = k0 + kk;
            Bs[kk][nn] = (k < K && n < H) ? W[(size_t)n * K + k] : 0.f;
        }
        __syncthreads();
        #pragma unroll
        for (int kk = 0; kk < BK; ++kk) {
            float a4[4], b4[4];
            #pragma unroll
            for (int i = 0; i < 4; ++i) a4[i] = As[kk][ty + 16 * i];
            #pragma unroll
            for (int j = 0; j < 4; ++j) b4[j] = Bs[kk][tx + 16 * j];
            #pragma unroll
            for (int i = 0; i < 4; ++i)
                #pragma unroll
                for (int j = 0; j < 4; ++j) acc[i][j] += a4[i] * b4[j];
        }
        __syncthreads();
    }

    #pragma unroll
    for (int i = 0; i < 4; ++i) {
        int m = m0 + ty + 16 * i;
        #pragma unroll
        for (int j = 0; j < 4; ++j) {
            int n = n0 + tx + 16 * j;
            if (n < H) {
                float v = acc[i][j] + bl[n];
                if (relu) v = fmaxf(v, 0.f);
                v += res[(size_t)m * H + n];
                out[(size_t)m * H + n] = v;
            }
        }
    }
}

extern "C" void kernel_launch(void* const* d_in, const int* in_sizes, int n_in,
                              void* d_out, int out_size, void* d_ws, size_t ws_size,
                              hipStream_t stream) {
    const float* x = (const float*)d_in[0];

    char* ws = (char*)d_ws;
    __half* pre = (__half*)ws;                                   // 2*32000*644 halves = 82.4 MB
    float* hcat = (float*)(ws + (size_t)2 * M_TOT * G4 * sizeof(__half));
    float* bufA = hcat + (size_t)M_TOT * 2 * H;                  // 41.2 MB after hcat
    float* bufB = bufA + (size_t)M_TOT * H;                      // 20.6 MB each

    const float* cur = x;
    float* outs[3] = {bufA, bufB, (float*)d_out};

    for (int l = 0; l < 3; ++l) {
        const float* const* p = (const float* const*)(d_in + 1 + 10 * l);
        // p: wih_f whh_f bih_f bhh_f wih_b whh_b bih_b bhh_b W bl
        dim3 g1(M_TOT / 64, 21);
        pre_gemm<<<g1, 256, 0, stream>>>(cur, p[0], p[4], p[2], p[3], p[6], p[7], pre);
        lstm_scan<<<dim3(32, 2), 704, 0, stream>>>(pre, p[1], p[5], hcat);
        dim3 g2(M_TOT / 64, 3);
        lin_gemm<<<g2, 256, 0, stream>>>(hcat, p[8], p[9], cur, outs[l], (l < 2) ? 1 : 0);
        cur = outs[l];
    }
}

// Round 3
// 4916.364 us; speedup vs baseline: 1.1684x; 1.1684x over previous
//
#include <hip/hip_runtime.h>
#include <hip/hip_fp16.h>

#define H 161
#define G4 644            // 4*H gates
#define BB 32             // batch
#define TT 1000           // time
#define M_TOT (BB*TT)     // 32000 rows
#define KPAD 192          // h padded to 192 halfs (4 quarters of 48)
#define KQ 24             // half2 pairs per quarter

typedef _Float16 h2_t __attribute__((ext_vector_type(2)));

__device__ __forceinline__ h2_t bc_h2(unsigned int u) {
    return __builtin_bit_cast(h2_t, u);
}

__device__ __forceinline__ float dot2f(h2_t a, h2_t b, float c) {
#if __has_builtin(__builtin_amdgcn_fdot2)
    return __builtin_amdgcn_fdot2(a, b, c, false);
#else
    return c + (float)a[0] * (float)b[0] + (float)a[1] * (float)b[1];
#endif
}

__device__ __forceinline__ float sigm_f(float x) {
    return 1.0f / (1.0f + __expf(-x));
}
__device__ __forceinline__ float tanh_f(float x) {
    return 1.0f - 2.0f / (__expf(2.0f * x) + 1.0f);
}

// In-quad all-reduce via DPP quad_perm (xor1 then xor2). Quads are wholly
// active or wholly inactive (644 = 4*161), so source lanes are safe.
template<int CTRL>
__device__ __forceinline__ float dpp_addf(float x) {
    int y = __builtin_amdgcn_update_dpp(0, __builtin_bit_cast(int, x), CTRL, 0xF, 0xF, true);
    return x + __builtin_bit_cast(float, y);
}
__device__ __forceinline__ float qsum(float x) {
    x = dpp_addf<0xB1>(x);
    x = dpp_addf<0x4E>(x);
    return x;
}

// Barrier draining only LDS (lgkmcnt), not vmcnt: hcat stores and the
// 4-deep pre prefetch stay in flight across step boundaries.
__device__ __forceinline__ void bar_lds() {
    __builtin_amdgcn_sched_barrier(0);
    asm volatile("s_waitcnt lgkmcnt(0)" ::: "memory");
    __builtin_amdgcn_s_barrier();
    __builtin_amdgcn_sched_barrier(0);
}

// ---------------------------------------------------------------------------
// pre_gemm: pre[d][m][col*4+gate] = sum_k A[m][k]*wih_d[gate*H+col][k] + biases
// ---------------------------------------------------------------------------
__global__ __launch_bounds__(256) void pre_gemm(
    const float* __restrict__ A,
    const float* __restrict__ wf, const float* __restrict__ wb,
    const float* __restrict__ bif, const float* __restrict__ bhf,
    const float* __restrict__ bib, const float* __restrict__ bhb,
    __half* __restrict__ pre)
{
    const int BM = 64, BN = 64, BK = 16;
    int m0 = blockIdx.x * BM;
    int n0 = blockIdx.y * BN;
    __shared__ float As[BK][BM + 1];
    __shared__ float Bs[BK][BN + 1];
    int tid = threadIdx.x;
    int tx = tid & 15, ty = tid >> 4;
    float acc[4][4] = {};

    for (int k0 = 0; k0 < H; k0 += BK) {
        #pragma unroll
        for (int l = 0; l < (BM * BK) / 256; ++l) {
            int e = tid + l * 256;
            int mm = e / BK, kk = e % BK;
            int k = k0 + kk;
            As[kk][mm] = (k < H) ? A[(size_t)(m0 + mm) * H + k] : 0.f;
        }
        #pragma unroll
        for (int l = 0; l < (BN * BK) / 256; ++l) {
            int e = tid + l * 256;
            int nn = e / BK, kk = e % BK;
            int n = n0 + nn, k = k0 + kk;
            float v = 0.f;
            if (k < H && n < 2 * G4)
                v = (n < G4) ? wf[(size_t)n * H + k] : wb[(size_t)(n - G4) * H + k];
            Bs[kk][nn] = v;
        }
        __syncthreads();
        #pragma unroll
        for (int kk = 0; kk < BK; ++kk) {
            float a4[4], b4[4];
            #pragma unroll
            for (int i = 0; i < 4; ++i) a4[i] = As[kk][ty + 16 * i];
            #pragma unroll
            for (int j = 0; j < 4; ++j) b4[j] = Bs[kk][tx + 16 * j];
            #pragma unroll
            for (int i = 0; i < 4; ++i)
                #pragma unroll
                for (int j = 0; j < 4; ++j) acc[i][j] += a4[i] * b4[j];
        }
        __syncthreads();
    }

    #pragma unroll
    for (int i = 0; i < 4; ++i) {
        int m = m0 + ty + 16 * i;
        #pragma unroll
        for (int j = 0; j < 4; ++j) {
            int n = n0 + tx + 16 * j;
            if (n < 2 * G4) {
                int d = (n >= G4) ? 1 : 0;
                int g = n - d * G4;
                int gate = g / H;
                int col = g - gate * H;
                float bias = d ? (bib[g] + bhb[g]) : (bif[g] + bhf[g]);
                pre[((size_t)d * M_TOT + m) * G4 + col * 4 + gate] =
                    __float2half(acc[i][j] + bias);
            }
        }
    }
}

// ---------------------------------------------------------------------------
// lstm_scan, quad layout + 4-deep software-pipelined pre prefetch.
// ---------------------------------------------------------------------------
__global__ __launch_bounds__(704, 1) void lstm_scan(
    const __half* __restrict__ pre,      // [2][M_TOT][G4], col*4+gate layout
    const float* __restrict__ whh_f,
    const float* __restrict__ whh_b,
    float* __restrict__ hcat)            // [M_TOT][2*H]
{
    const int b = blockIdx.x;            // 0..31
    const int d = blockIdx.y;            // 0,1
    const int tid = threadIdx.x;
    const float* whh = d ? whh_b : whh_f;

    __shared__ __align__(16) unsigned int h_sh[2][KPAD / 2];  // 2 x 192 halfs

    const int q  = tid >> 2;                 // column 0..175
    const int qc = (q < H) ? q : (H - 1);    // clamped for inactive lanes
    const int s  = tid & 3;                  // k-quarter / gate-seed index
    const bool writer = (tid < G4) && (s == 0);

    // Flat uint weight storage, unconditional clamped init.
    unsigned int w[4 * KQ];
    #pragma unroll
    for (int g = 0; g < 4; ++g) {
        const float* row = whh + (size_t)(g * H + qc) * H;
        #pragma unroll
        for (int i = 0; i < KQ; ++i) {
            int k = s * 48 + 2 * i;
            float w0 = (k < H) ? row[k] : 0.f;
            float w1 = (k + 1 < H) ? row[k + 1] : 0.f;
            h2_t v; v[0] = (_Float16)w0; v[1] = (_Float16)w1;
            w[g * KQ + i] = __builtin_bit_cast(unsigned int, v);
        }
    }
    if (tid < KPAD / 2) { h_sh[0][tid] = 0u; h_sh[1][tid] = 0u; }

    float c = 0.f;
    const int lid = (tid < G4) ? tid : (G4 - 1);  // clamped pre lane
    const __half* pb = pre + ((size_t)d * M_TOT + (size_t)b * TT) * G4 + lid;

    #define LDPRE(ttt_) ({                                                  \
        int tc_ = ((ttt_) < TT) ? (ttt_) : (TT - 1);                        \
        int t_  = d ? (TT - 1 - tc_) : tc_;                                 \
        __half2float(pb[(size_t)t_ * G4]); })

    float p0 = LDPRE(0), p1 = LDPRE(1), p2 = LDPRE(2), p3 = LDPRE(3);
    __syncthreads();

    #define STEP(J, PJ) {                                                   \
        int ttt = base + (J);                                               \
        int t = d ? (TT - 1 - ttt) : ttt;                                   \
        float a0 = (s == 0) ? PJ : 0.f;                                     \
        float a1 = (s == 1) ? PJ : 0.f;                                     \
        float a2 = (s == 2) ? PJ : 0.f;                                     \
        float a3 = (s == 3) ? PJ : 0.f;                                     \
        PJ = LDPRE(base + 4 + (J));     /* issue 4-steps-ahead load */      \
        const uint4* h4 = (const uint4*)(h_sh[(J) & 1]);                    \
        _Pragma("unroll")                                                   \
        for (int i = 0; i < 6; ++i) {                                       \
            uint4 hh = h4[s * 6 + i];                                       \
            h2_t hx = bc_h2(hh.x), hy = bc_h2(hh.y);                        \
            h2_t hz = bc_h2(hh.z), hw = bc_h2(hh.w);                        \
            a0 = dot2f(bc_h2(w[0*KQ+4*i+0]), hx, a0);                       \
            a0 = dot2f(bc_h2(w[0*KQ+4*i+1]), hy, a0);                       \
            a0 = dot2f(bc_h2(w[0*KQ+4*i+2]), hz, a0);                       \
            a0 = dot2f(bc_h2(w[0*KQ+4*i+3]), hw, a0);                       \
            a1 = dot2f(bc_h2(w[1*KQ+4*i+0]), hx, a1);                       \
            a1 = dot2f(bc_h2(w[1*KQ+4*i+1]), hy, a1);                       \
            a1 = dot2f(bc_h2(w[1*KQ+4*i+2]), hz, a1);                       \
            a1 = dot2f(bc_h2(w[1*KQ+4*i+3]), hw, a1);                       \
            a2 = dot2f(bc_h2(w[2*KQ+4*i+0]), hx, a2);                       \
            a2 = dot2f(bc_h2(w[2*KQ+4*i+1]), hy, a2);                       \
            a2 = dot2f(bc_h2(w[2*KQ+4*i+2]), hz, a2);                       \
            a2 = dot2f(bc_h2(w[2*KQ+4*i+3]), hw, a2);                       \
            a3 = dot2f(bc_h2(w[3*KQ+4*i+0]), hx, a3);                       \
            a3 = dot2f(bc_h2(w[3*KQ+4*i+1]), hy, a3);                       \
            a3 = dot2f(bc_h2(w[3*KQ+4*i+2]), hz, a3);                       \
            a3 = dot2f(bc_h2(w[3*KQ+4*i+3]), hw, a3);                       \
        }                                                                   \
        a0 = qsum(a0); a1 = qsum(a1); a2 = qsum(a2); a3 = qsum(a3);         \
        float ig = sigm_f(a0);                                              \
        float fg = sigm_f(a1);                                              \
        float gg = tanh_f(a2);                                              \
        float og = sigm_f(a3);                                              \
        c = fg * c + ig * gg;                                               \
        float hval = og * tanh_f(c);                                        \
        if (writer) {                                                       \
            hcat[((size_t)b * TT + t) * (2 * H) + (size_t)d * H + q] = hval;\
            ((__half*)h_sh[((J) & 1) ^ 1])[q] = __float2half(hval);         \
        }                                                                   \
        bar_lds();                                                          \
    }

    for (int base = 0; base < TT; base += 4) {
        STEP(0, p0)
        STEP(1, p1)
        STEP(2, p2)
        STEP(3, p3)
    }
    #undef STEP
    #undef LDPRE
}

// ---------------------------------------------------------------------------
// lin_gemm: out[m][n] = relu?(sum_k hcat[m][k]*W[n][k] + bl[n]) + res[m][n]
// ---------------------------------------------------------------------------
__global__ __launch_bounds__(256) void lin_gemm(
    const float* __restrict__ A,     // [M_TOT][2H]
    const float* __restrict__ W,     // [H][2H]
    const float* __restrict__ bl,    // [H]
    const float* __restrict__ res,   // [M_TOT][H]
    float* __restrict__ out,         // [M_TOT][H]
    int relu)
{
    const int BM = 64, BN = 64, BK = 16;
    const int K = 2 * H;
    int m0 = blockIdx.x * BM;
    int n0 = blockIdx.y * BN;
    __shared__ float As[BK][BM + 1];
    __shared__ float Bs[BK][BN + 1];
    int tid = threadIdx.x;
    int tx = tid & 15, ty = tid >> 4;
    float acc[4][4] = {};

    for (int k0 = 0; k0 < K; k0 += BK) {
        #pragma unroll
        for (int l = 0; l < (BM * BK) / 256; ++l) {
            int e = tid + l * 256;
            int mm = e / BK, kk = e % BK;
            int k = k0 + kk;
            As[kk][mm] = (k < K) ? A[(size_t)(m0 + mm) * K + k] : 0.f;
        }
        #pragma unroll
        for (int l = 0; l < (BN * BK) / 256; ++l) {
            int e = tid + l * 256;
            int nn = e / BK, kk = e % BK;
            int n = n0 + nn, k = k0 + kk;
            Bs[kk][nn] = (k < K && n < H) ? W[(size_t)n * K + k] : 0.f;
        }
        __syncthreads();
        #pragma unroll
        for (int kk = 0; kk < BK; ++kk) {
            float a4[4], b4[4];
            #pragma unroll
            for (int i = 0; i < 4; ++i) a4[i] = As[kk][ty + 16 * i];
            #pragma unroll
            for (int j = 0; j < 4; ++j) b4[j] = Bs[kk][tx + 16 * j];
            #pragma unroll
            for (int i = 0; i < 4; ++i)
                #pragma unroll
                for (int j = 0; j < 4; ++j) acc[i][j] += a4[i] * b4[j];
        }
        __syncthreads();
    }

    #pragma unroll
    for (int i = 0; i < 4; ++i) {
        int m = m0 + ty + 16 * i;
        #pragma unroll
        for (int j = 0; j < 4; ++j) {
            int n = n0 + tx + 16 * j;
            if (n < H) {
                float v = acc[i][j] + bl[n];
                if (relu) v = fmaxf(v, 0.f);
                v += res[(size_t)m * H + n];
                out[(size_t)m * H + n] = v;
            }
        }
    }
}

extern "C" void kernel_launch(void* const* d_in, const int* in_sizes, int n_in,
                              void* d_out, int out_size, void* d_ws, size_t ws_size,
                              hipStream_t stream) {
    const float* x = (const float*)d_in[0];

    char* ws = (char*)d_ws;
    __half* pre = (__half*)ws;                                   // 82.4 MB
    float* hcat = (float*)(ws + (size_t)2 * M_TOT * G4 * sizeof(__half));
    float* bufA = hcat + (size_t)M_TOT * 2 * H;
    float* bufB = bufA + (size_t)M_TOT * H;

    const float* cur = x;
    float* outs[3] = {bufA, bufB, (float*)d_out};

    for (int l = 0; l < 3; ++l) {
        const float* const* p = (const float* const*)(d_in + 1 + 10 * l);
        dim3 g1(M_TOT / 64, 21);
        pre_gemm<<<g1, 256, 0, stream>>>(cur, p[0], p[4], p[2], p[3], p[6], p[7], pre);
        lstm_scan<<<dim3(32, 2), 704, 0, stream>>>(pre, p[1], p[5], hcat);
        dim3 g2(M_TOT / 64, 3);
        lin_gemm<<<g2, 256, 0, stream>>>(hcat, p[8], p[9], cur, outs[l], (l < 2) ? 1 : 0);
        cur = outs[l];
    }
}